// Round 11
// baseline (139.210 us; speedup 1.0000x reference)
//
#include <hip/hip_runtime.h>
#include <hip/hip_bf16.h>

#define NB 8
#define NN 2048
#define NF 64      // in features
#define NP 64      // out features per head
#define NH 4
#define NHF 256    // NH*NP
#define LOG2E 1.4426950408889634f

typedef float f32x4 __attribute__((ext_vector_type(4)));
typedef short bf16x8 __attribute__((ext_vector_type(8)));
typedef short s16x4 __attribute__((ext_vector_type(4)));

// f32 -> bf16 bits, round-nearest-even
__device__ __forceinline__ short f2bf(float f) {
    unsigned u = __builtin_bit_cast(unsigned, f);
    unsigned r = (u + 0x7fffu + ((u >> 16) & 1u)) >> 16;
    return (short)r;
}

__device__ __forceinline__ float exp2_fast(float x) {
#if __has_builtin(__builtin_amdgcn_exp2f)
    return __builtin_amdgcn_exp2f(x);
#else
    float r;
    asm volatile("v_exp_f32 %0, %1\n\ts_nop 1" : "=v"(r) : "v"(x));
    return r;
#endif
}

// ---------------------------------------------------------------------------
// Kernel A1: s_out[b,h,n] = (x[b,n,:] . (W[h] @ a_out[h])) * LOG2E, same s_in.
// ---------------------------------------------------------------------------
__global__ __launch_bounds__(256) void gat_scores(
    const float* __restrict__ x, const float* __restrict__ W,
    const float* __restrict__ a_out, const float* __restrict__ a_in,
    float* __restrict__ s_out, float* __restrict__ s_in)
{
    __shared__ float co_lds[NH][NF];
    __shared__ float ci_lds[NH][NF];
    int tid = threadIdx.x;
    int h = tid >> 6, f = tid & 63;
    {
        float co = 0.f, ci = 0.f;
        const float* wrow = W + (h * NF + f) * NP;
        #pragma unroll 8
        for (int o = 0; o < NP; ++o) {
            float w = wrow[o];
            co = fmaf(w, a_out[h * NP + o], co);
            ci = fmaf(w, a_in[h * NP + o], ci);
        }
        co_lds[h][f] = co;
        ci_lds[h][f] = ci;
    }
    __syncthreads();
    int wid = tid >> 6, lane = tid & 63;
    float cov[NH], civ[NH];
    #pragma unroll
    for (int hh = 0; hh < NH; ++hh) { cov[hh] = co_lds[hh][lane]; civ[hh] = ci_lds[hh][lane]; }
    int base = blockIdx.x * 64 + wid * 16;     // global row in [0, B*N)
    for (int r = 0; r < 16; ++r) {
        int gn = base + r;
        float xv = x[(size_t)gn * NF + lane];
        #pragma unroll
        for (int hh = 0; hh < NH; ++hh) {
            float vo = xv * cov[hh];
            float vi = xv * civ[hh];
            #pragma unroll
            for (int s2 = 1; s2 < 64; s2 <<= 1) {
                vo += __shfl_xor(vo, s2, 64);
                vi += __shfl_xor(vi, s2, 64);
            }
            if (lane == 0) {
                int b = gn >> 11, n = gn & (NN - 1);
                s_out[((size_t)b * NH + hh) * NN + n] = vo * LOG2E;
                s_in [((size_t)b * NH + hh) * NN + n] = vi * LOG2E;
            }
        }
    }
}

// ---------------------------------------------------------------------------
// Kernel A2: featsT interleaved: element (feature o, node j) of head (b,h) at
// base(b,h) + (j>>3)*512 + o*8 + (j&7)  => V-frag loads are 256B-contiguous.
// ---------------------------------------------------------------------------
__global__ __launch_bounds__(256) void gat_feats(
    const float* __restrict__ x, const float* __restrict__ W,
    short* __restrict__ featsT)
{
    int blk = blockIdx.x;
    int nb = blk & 31;           // N/64 = 32
    int h  = (blk >> 5) & 3;
    int b  = blk >> 7;
    int tid = threadIdx.x, wid = tid >> 6, lane = tid & 63;
    int n0 = nb * 64 + wid * 16;
    int rA = lane & 15, g = lane >> 4;

    bf16x8 af[2];
    #pragma unroll
    for (int kk = 0; kk < 2; ++kk) {
        const float* xp = x + ((size_t)(b * NN) + n0 + rA) * NF + kk * 32 + g * 8;
        f32x4 x0 = *(const f32x4*)xp;
        f32x4 x1 = *(const f32x4*)(xp + 4);
        #pragma unroll
        for (int e = 0; e < 4; ++e) {
            af[kk][e]     = f2bf(x0[e]);
            af[kk][e + 4] = f2bf(x1[e]);
        }
    }
    f32x4 acc[4] = {};
    #pragma unroll
    for (int o = 0; o < 4; ++o) {
        #pragma unroll
        for (int kk = 0; kk < 2; ++kk) {
            bf16x8 bfv;
            #pragma unroll
            for (int e = 0; e < 8; ++e) {
                float wv = W[((size_t)h * NF + kk * 32 + g * 8 + e) * NP + o * 16 + rA];
                bfv[e] = f2bf(wv);
            }
            acc[o] = __builtin_amdgcn_mfma_f32_16x16x32_bf16(af[kk], bfv, acc[o], 0, 0, 0);
        }
    }
    size_t hb = (size_t)(b * NH + h) * NP * NN;
    int jq = n0 / 8 + (g >> 1);     // j>>3 for j = n0 + g*4
    int jr = (g & 1) * 4;           // j&7
    #pragma unroll
    for (int o = 0; o < 4; ++o) {
        s16x4 pk;
        pk[0] = f2bf(acc[o][0]);
        pk[1] = f2bf(acc[o][1]);
        pk[2] = f2bf(acc[o][2]);
        pk[3] = f2bf(acc[o][3]);
        *(s16x4*)(featsT + hb + (size_t)jq * 512 + (o * 16 + rA) * 8 + jr) = pk;
    }
}

// ---------------------------------------------------------------------------
// Kernel B: fused masked-softmax attention + PV. BARRIER-FREE, LDS-FREE.
// Grid: B*(N/16) = 1024 blocks x 256 thr (4 waves = 4 heads, 16 i-rows).
// Each wave fully independent. adj read directly per-lane from global: all 4
// waves of a block read the SAME 16 adj rows -> wave 1 warms L1, waves 2-4
// hit L1 (16KB slice); HBM traffic unchanged vs LDS staging, but no barriers,
// no vmcnt(0) drains, no async-LDS FIFO entanglement. 2-deep named-register
// software pipeline (stage = 32 VGPR; waves_per_eu(4,4) -> 128 VGPR budget,
// the R3 spill trap avoided). XCD swizzle keeps featsT slice L2-resident.
// exp2-domain P; denominator via 5th MFMA against all-ones B.
// ---------------------------------------------------------------------------
__global__ __launch_bounds__(256)
__attribute__((amdgpu_waves_per_eu(4, 4)))
void gat_attn(
    const float* __restrict__ adj,     // [B,N,N]
    const short* __restrict__ featsT,  // interleaved, see gat_feats
    const float* __restrict__ s_out,   // [B,H,N]  (prescaled by log2e)
    const float* __restrict__ s_in,    // [B,H,N]  (prescaled by log2e)
    const float* __restrict__ biases,  // [H,FP]
    float* __restrict__ out)           // [B,N,H*FP]
{
    // XCD swizzle: grid 1024 = 8 XCD x 128; XCD x owns batch x entirely.
    int blk = ((blockIdx.x & 7) << 7) + (blockIdx.x >> 3);
    int b  = blk >> 7;            // 128 i-tiles per batch
    int it = blk & 127;
    int i0 = it * 16;
    int tid = threadIdx.x;
    int h = tid >> 6;             // wave = head
    int lane = tid & 63;
    int r  = lane & 15;           // A-frag row / B-frag col
    int jg = lane >> 4;           // k-group: this lane covers j = c*32+jg*8+e

    float so = s_out[((size_t)b * NH + h) * NN + i0 + r];
    const float* arow  = adj + ((size_t)b * NN + i0 + r) * NN + jg * 8;
    const float* sirow = s_in + ((size_t)b * NH + h) * NN + jg * 8;
    const short* vwave = featsT + (size_t)(b * NH + h) * NP * NN + jg * 512 + r * 8;

    float bias_v[4];
    #pragma unroll
    for (int o = 0; o < 4; ++o) bias_v[o] = biases[h * NP + o * 16 + r];

    bf16x8 ones;
    #pragma unroll
    for (int e = 0; e < 8; ++e) ones[e] = (short)0x3F80;   // bf16 1.0

    f32x4 acc0 = {}, acc1 = {}, acc2 = {}, acc3 = {};
    f32x4 acc4 = {};   // row-sum accumulator (denominator)

    // named pipeline stages (no arrays -> no scratch, rule #20)
    f32x4 Aa0, Aa1, Aq0, Aq1, Ba0, Ba1, Bq0, Bq1;
    bf16x8 Av0, Av1, Av2, Av3, Bv0, Bv1, Bv2, Bv3;

#define LOADC(P, C) do {                                                      \
        const float* ap_ = arow + (C) * 32;                                   \
        P##a0 = *(const f32x4*)(ap_);                                         \
        P##a1 = *(const f32x4*)(ap_ + 4);                                     \
        const float* sp_ = sirow + (C) * 32;                                  \
        P##q0 = *(const f32x4*)(sp_);                                         \
        P##q1 = *(const f32x4*)(sp_ + 4);                                     \
        const short* vp_ = vwave + (C) * 2048;                                \
        P##v0 = *(const bf16x8*)(vp_);                                        \
        P##v1 = *(const bf16x8*)(vp_ + 128);                                  \
        P##v2 = *(const bf16x8*)(vp_ + 256);                                  \
        P##v3 = *(const bf16x8*)(vp_ + 384);                                  \
    } while (0)

#define COMPUTE(P) do {                                                       \
        bf16x8 af;                                                            \
        _Pragma("unroll")                                                     \
        for (int e = 0; e < 8; ++e) {                                         \
            float av = (e < 4) ? P##a0[e] : P##a1[e - 4];                     \
            float sv = (e < 4) ? P##q0[e] : P##q1[e - 4];                     \
            float t = so + sv;                                                \
            float lr = fmaxf(t, 0.2f * t);                                    \
            float arg = fmaf(av, LOG2E, lr);                                  \
            float pe_ = exp2_fast(arg);                                       \
            float p = (av != 0.f) ? pe_ : 0.f;                                \
            __hip_bfloat16 hbv = __float2bfloat16(p);                         \
            af[e] = (short)__builtin_bit_cast(unsigned short, hbv);           \
        }                                                                     \
        acc0 = __builtin_amdgcn_mfma_f32_16x16x32_bf16(af, P##v0, acc0, 0, 0, 0); \
        acc1 = __builtin_amdgcn_mfma_f32_16x16x32_bf16(af, P##v1, acc1, 0, 0, 0); \
        acc2 = __builtin_amdgcn_mfma_f32_16x16x32_bf16(af, P##v2, acc2, 0, 0, 0); \
        acc3 = __builtin_amdgcn_mfma_f32_16x16x32_bf16(af, P##v3, acc3, 0, 0, 0); \
        acc4 = __builtin_amdgcn_mfma_f32_16x16x32_bf16(af, ones, acc4, 0, 0, 0); \
    } while (0)

    // 64 chunks of 32 j; 2-deep pipeline, branch-free steady state.
    LOADC(A, 0);
    LOADC(B, 1);
    for (int c = 0; c < 62; c += 2) {
        COMPUTE(A); LOADC(A, c + 2);
        COMPUTE(B); LOADC(B, c + 3);
    }
    COMPUTE(A);   // chunk 62
    COMPUTE(B);   // chunk 63
#undef LOADC
#undef COMPUTE

    // epilogue: denominator for row (jg*4+reg) is acc4[reg] in every lane of
    // the matching group (all-ones B => every column holds the row sum).
    #pragma unroll
    for (int reg = 0; reg < 4; ++reg) {
        int row = jg * 4 + reg;                  // D row = (lane>>4)*4 + reg
        float rcp = 1.0f / acc4[reg];
        float* orow = out + ((size_t)b * NN + i0 + row) * NHF + h * NP;
        float a0v = (reg == 0) ? acc0[0] : (reg == 1) ? acc0[1] : (reg == 2) ? acc0[2] : acc0[3];
        float a1v = (reg == 0) ? acc1[0] : (reg == 1) ? acc1[1] : (reg == 2) ? acc1[2] : acc1[3];
        float a2v = (reg == 0) ? acc2[0] : (reg == 1) ? acc2[1] : (reg == 2) ? acc2[2] : acc2[3];
        float a3v = (reg == 0) ? acc3[0] : (reg == 1) ? acc3[1] : (reg == 2) ? acc3[2] : acc3[3];
        float y0 = a0v * rcp + bias_v[0];
        float y1 = a1v * rcp + bias_v[1];
        float y2 = a2v * rcp + bias_v[2];
        float y3 = a3v * rcp + bias_v[3];
        y0 = (y0 > 0.f) ? y0 : (__expf(y0) - 1.0f);
        y1 = (y1 > 0.f) ? y1 : (__expf(y1) - 1.0f);
        y2 = (y2 > 0.f) ? y2 : (__expf(y2) - 1.0f);
        y3 = (y3 > 0.f) ? y3 : (__expf(y3) - 1.0f);
        orow[0 * 16 + r] = y0;
        orow[1 * 16 + r] = y1;
        orow[2 * 16 + r] = y2;
        orow[3 * 16 + r] = y3;
    }
}

extern "C" void kernel_launch(void* const* d_in, const int* in_sizes, int n_in,
                              void* d_out, int out_size, void* d_ws, size_t ws_size,
                              hipStream_t stream) {
    const float* x      = (const float*)d_in[0];  // node_feats [B,N,F]
    const float* adj    = (const float*)d_in[1];  // adjacency  [B,N,N]
    // d_in[2] = attn_mask -- NOT read; derived from adj (edge <=> adj != 0)
    const float* W      = (const float*)d_in[3];  // kernels    [H,F,FP]
    const float* biases = (const float*)d_in[4];  // [H,FP]
    const float* a_out  = (const float*)d_in[5];  // [H,FP]
    const float* a_in   = (const float*)d_in[6];  // [H,FP]
    float* out = (float*)d_out;

    char* ws = (char*)d_ws;
    short* featsT = (short*)ws;                                // 8 MB bf16, interleaved
    float* s_out  = (float*)(ws + 8388608);                    // 256 KB
    float* s_in   = (float*)(ws + 8388608 + 262144);           // 256 KB

    gat_scores<<<256, 256, 0, stream>>>(x, W, a_out, a_in, s_out, s_in);
    gat_feats<<<NB * NH * (NN / 64), 256, 0, stream>>>(x, W, featsT);
    gat_attn<<<NB * (NN / 16), 256, 0, stream>>>(adj, featsT, s_out, s_in, biases, out);
}

// Round 12
// 108.017 us; speedup vs baseline: 1.2888x; 1.2888x over previous
//
#include <hip/hip_runtime.h>
#include <hip/hip_bf16.h>

#define NB 8
#define NN 2048
#define NF 64      // in features
#define NP 64      // out features per head
#define NH 4
#define NHF 256    // NH*NP
#define LOG2E 1.4426950408889634f

typedef float f32x4 __attribute__((ext_vector_type(4)));
typedef short bf16x8 __attribute__((ext_vector_type(8)));
typedef short s16x4 __attribute__((ext_vector_type(4)));

// f32 -> bf16 bits, round-nearest-even
__device__ __forceinline__ short f2bf(float f) {
    unsigned u = __builtin_bit_cast(unsigned, f);
    unsigned r = (u + 0x7fffu + ((u >> 16) & 1u)) >> 16;
    return (short)r;
}

__device__ __forceinline__ float exp2_fast(float x) {
#if __has_builtin(__builtin_amdgcn_exp2f)
    return __builtin_amdgcn_exp2f(x);
#else
    float r;
    asm volatile("v_exp_f32 %0, %1\n\ts_nop 1" : "=v"(r) : "v"(x));
    return r;
#endif
}

__device__ __forceinline__ void async16(const void* g, void* l) {
    __builtin_amdgcn_global_load_lds(
        (const __attribute__((address_space(1))) void*)g,
        (__attribute__((address_space(3))) void*)l, 16, 0, 0);
}

// Full drain before barrier: LDS-DMA (global_load_lds) must complete before
// any wave crosses (R7 replay-race lesson).
#define DRAIN_BARRIER() do {                                                  \
        asm volatile("s_waitcnt vmcnt(0) lgkmcnt(0)" ::: "memory");           \
        __syncthreads();                                                      \
    } while (0)

// ---------------------------------------------------------------------------
// Kernel A1: s_out[b,h,n] = (x[b,n,:] . (W[h] @ a_out[h])) * LOG2E, same s_in.
// ---------------------------------------------------------------------------
__global__ __launch_bounds__(256) void gat_scores(
    const float* __restrict__ x, const float* __restrict__ W,
    const float* __restrict__ a_out, const float* __restrict__ a_in,
    float* __restrict__ s_out, float* __restrict__ s_in)
{
    __shared__ float co_lds[NH][NF];
    __shared__ float ci_lds[NH][NF];
    int tid = threadIdx.x;
    int h = tid >> 6, f = tid & 63;
    {
        float co = 0.f, ci = 0.f;
        const float* wrow = W + (h * NF + f) * NP;
        #pragma unroll 8
        for (int o = 0; o < NP; ++o) {
            float w = wrow[o];
            co = fmaf(w, a_out[h * NP + o], co);
            ci = fmaf(w, a_in[h * NP + o], ci);
        }
        co_lds[h][f] = co;
        ci_lds[h][f] = ci;
    }
    __syncthreads();
    int wid = tid >> 6, lane = tid & 63;
    float cov[NH], civ[NH];
    #pragma unroll
    for (int hh = 0; hh < NH; ++hh) { cov[hh] = co_lds[hh][lane]; civ[hh] = ci_lds[hh][lane]; }
    int base = blockIdx.x * 64 + wid * 16;     // global row in [0, B*N)
    for (int r = 0; r < 16; ++r) {
        int gn = base + r;
        float xv = x[(size_t)gn * NF + lane];
        #pragma unroll
        for (int hh = 0; hh < NH; ++hh) {
            float vo = xv * cov[hh];
            float vi = xv * civ[hh];
            #pragma unroll
            for (int s2 = 1; s2 < 64; s2 <<= 1) {
                vo += __shfl_xor(vo, s2, 64);
                vi += __shfl_xor(vi, s2, 64);
            }
            if (lane == 0) {
                int b = gn >> 11, n = gn & (NN - 1);
                s_out[((size_t)b * NH + hh) * NN + n] = vo * LOG2E;
                s_in [((size_t)b * NH + hh) * NN + n] = vi * LOG2E;
            }
        }
    }
}

// ---------------------------------------------------------------------------
// Kernel A2: featsT interleaved: element (feature o, node j) of head (b,h) at
// base(b,h) + (j>>3)*512 + o*8 + (j&7)  => V-frag loads are 256B-contiguous.
// ---------------------------------------------------------------------------
__global__ __launch_bounds__(256) void gat_feats(
    const float* __restrict__ x, const float* __restrict__ W,
    short* __restrict__ featsT)
{
    int blk = blockIdx.x;
    int nb = blk & 31;           // N/64 = 32
    int h  = (blk >> 5) & 3;
    int b  = blk >> 7;
    int tid = threadIdx.x, wid = tid >> 6, lane = tid & 63;
    int n0 = nb * 64 + wid * 16;
    int rA = lane & 15, g = lane >> 4;

    bf16x8 af[2];
    #pragma unroll
    for (int kk = 0; kk < 2; ++kk) {
        const float* xp = x + ((size_t)(b * NN) + n0 + rA) * NF + kk * 32 + g * 8;
        f32x4 x0 = *(const f32x4*)xp;
        f32x4 x1 = *(const f32x4*)(xp + 4);
        #pragma unroll
        for (int e = 0; e < 4; ++e) {
            af[kk][e]     = f2bf(x0[e]);
            af[kk][e + 4] = f2bf(x1[e]);
        }
    }
    f32x4 acc[4] = {};
    #pragma unroll
    for (int o = 0; o < 4; ++o) {
        #pragma unroll
        for (int kk = 0; kk < 2; ++kk) {
            bf16x8 bfv;
            #pragma unroll
            for (int e = 0; e < 8; ++e) {
                float wv = W[((size_t)h * NF + kk * 32 + g * 8 + e) * NP + o * 16 + rA];
                bfv[e] = f2bf(wv);
            }
            acc[o] = __builtin_amdgcn_mfma_f32_16x16x32_bf16(af[kk], bfv, acc[o], 0, 0, 0);
        }
    }
    size_t hb = (size_t)(b * NH + h) * NP * NN;
    int jq = n0 / 8 + (g >> 1);     // j>>3 for j = n0 + g*4
    int jr = (g & 1) * 4;           // j&7
    #pragma unroll
    for (int o = 0; o < 4; ++o) {
        s16x4 pk;
        pk[0] = f2bf(acc[o][0]);
        pk[1] = f2bf(acc[o][1]);
        pk[2] = f2bf(acc[o][2]);
        pk[3] = f2bf(acc[o][3]);
        *(s16x4*)(featsT + hb + (size_t)jq * 512 + (o * 16 + rA) * 8 + jr) = pk;
    }
}

// ---------------------------------------------------------------------------
// Kernel B (split): partial attention over half the j-range.
// Grid: B*(N/16)*2 = 2048 blocks x 256 thr -> 8 blocks/CU, 32 waves/CU target.
// NO waves_per_eu attribute: allocator naturally picks ~64 VGPR (R8/R10/R11
// evidence); forcing (8,8) crushed it to 32 and spilled 100MB (R9 failure).
// XCD swizzle: 2048 = 8 XCD x 256; XCD x owns batch x -> featsT slice (1MB)
// L2-resident. STAGE at END of phase (R10 vmcnt-FIFO lesson).
// Super-chunk = 128 j, adj double-buffered (2 x 8 KB LDS).
// ---------------------------------------------------------------------------
__global__ __launch_bounds__(256) void gat_attn_part(
    const float* __restrict__ adj,     // [B,N,N]
    const short* __restrict__ featsT,  // interleaved
    const float* __restrict__ s_out,   // [B,H,N]  (prescaled by log2e)
    const float* __restrict__ s_in,    // [B,H,N]  (prescaled by log2e)
    float* __restrict__ part,          // [2,B,N,H*FP] partial numerators
    float* __restrict__ dpart)         // [2,B,H,N]  partial denominators
{
    __shared__ __align__(16) float adj_lds[2][2048];  // 2 x 8 KB (16 rows x 128 j)

    // XCD swizzle: XCD k gets raw blocks == k (mod 8) -> blk in [k*256,k*256+255]
    int blk = ((blockIdx.x & 7) << 8) | (blockIdx.x >> 3);
    int b   = blk >> 8;
    int rem = blk & 255;
    int it  = rem >> 1;
    int jh  = rem & 1;
    int i0 = it * 16;
    int j0 = jh << 10;            // 0 or 1024
    int tid = threadIdx.x;
    int h = tid >> 6;             // wave = head (wave-uniform)
    int lane = tid & 63;
    int r  = lane & 15;
    int jg = lane >> 4;

    // staging sources: call k covers rows h*4+2k (lanes 0-31) and +1 (32-63);
    // lane L fetches 16B block ((L&31) ^ (row&7)) of the row's 512B super-chunk.
    const char* asrc[2];
    #pragma unroll
    for (int k = 0; k < 2; ++k) {
        int row = h * 4 + 2 * k + (lane >> 5);
        asrc[k] = (const char*)(adj + ((size_t)b * NN + i0 + row) * NN + j0)
                  + (((lane & 31) ^ (row & 7)) << 4);
    }

#define STAGE(BUF, SC) do {                                                   \
        _Pragma("unroll")                                                     \
        for (int k = 0; k < 2; ++k)                                           \
            async16(asrc[k] + (SC) * 512,                                     \
                    &adj_lds[BUF][(h * 4 + 2 * k) << 7]);                     \
    } while (0)

    STAGE(0, 0);

    float so = s_out[((size_t)b * NH + h) * NN + i0 + r];
    const float* sirow = s_in + ((size_t)b * NH + h) * NN + j0 + jg * 8;
    const short* vwave = featsT + (size_t)(b * NH + h) * NP * NN
                         + (size_t)j0 * 64 + jg * 512 + r * 8;
    int rsw = r & 7;
    int f0 = ((jg * 2)     ^ rsw) << 2;
    int f1 = ((jg * 2 + 1) ^ rsw) << 2;
    int rbase = r << 7;                   // row stride = 128 floats (512B)

    bf16x8 ones;
    #pragma unroll
    for (int e = 0; e < 8; ++e) ones[e] = (short)0x3F80;   // bf16 1.0

    DRAIN_BARRIER();

    f32x4 acc[4] = {};
    f32x4 acc4 = {};

#define KSTEP(S, KS, Q0, Q1, V0, V1, V2, V3) do {                             \
        const float* ap = ab + rbase + (S) * 64 + (KS) * 32;                  \
        f32x4 a0 = *(const f32x4*)(ap + f0);                                  \
        f32x4 a1 = *(const f32x4*)(ap + f1);                                  \
        bf16x8 af;                                                            \
        _Pragma("unroll")                                                     \
        for (int e = 0; e < 8; ++e) {                                         \
            float av = (e < 4) ? a0[e] : a1[e - 4];                           \
            float sv = (e < 4) ? Q0[e] : Q1[e - 4];                           \
            float t = so + sv;                                                \
            float lr = fmaxf(t, 0.2f * t);                                    \
            float arg = fmaf(av, LOG2E, lr);                                  \
            float pe_ = exp2_fast(arg);                                       \
            float p = (av != 0.f) ? pe_ : 0.f;                                \
            __hip_bfloat16 hbv = __float2bfloat16(p);                         \
            af[e] = (short)__builtin_bit_cast(unsigned short, hbv);           \
        }                                                                     \
        acc[0] = __builtin_amdgcn_mfma_f32_16x16x32_bf16(af, V0, acc[0], 0, 0, 0); \
        acc[1] = __builtin_amdgcn_mfma_f32_16x16x32_bf16(af, V1, acc[1], 0, 0, 0); \
        acc[2] = __builtin_amdgcn_mfma_f32_16x16x32_bf16(af, V2, acc[2], 0, 0, 0); \
        acc[3] = __builtin_amdgcn_mfma_f32_16x16x32_bf16(af, V3, acc[3], 0, 0, 0); \
        acc4   = __builtin_amdgcn_mfma_f32_16x16x32_bf16(af, ones, acc4, 0, 0, 0); \
    } while (0)

#define SUB(SC, S) do {                                                       \
        const short* vp = vwave + ((SC) * 8192 + (S) * 4096);                 \
        bf16x8 v00 = *(const bf16x8*)(vp);                                    \
        bf16x8 v01 = *(const bf16x8*)(vp + 128);                              \
        bf16x8 v02 = *(const bf16x8*)(vp + 256);                              \
        bf16x8 v03 = *(const bf16x8*)(vp + 384);                              \
        bf16x8 v10 = *(const bf16x8*)(vp + 2048);                             \
        bf16x8 v11 = *(const bf16x8*)(vp + 2048 + 128);                       \
        bf16x8 v12 = *(const bf16x8*)(vp + 2048 + 256);                       \
        bf16x8 v13 = *(const bf16x8*)(vp + 2048 + 384);                       \
        const float* sip = sirow + (SC) * 128 + (S) * 64;                     \
        f32x4 q00 = *(const f32x4*)(sip);                                     \
        f32x4 q01 = *(const f32x4*)(sip + 4);                                 \
        f32x4 q10 = *(const f32x4*)(sip + 32);                                \
        f32x4 q11 = *(const f32x4*)(sip + 36);                                \
        KSTEP(S, 0, q00, q01, v00, v01, v02, v03);                            \
        KSTEP(S, 1, q10, q11, v10, v11, v12, v13);                            \
    } while (0)

    for (int sc = 0; sc < 8; ++sc) {
        int cur = sc & 1;
        const float* ab = &adj_lds[cur][0];
        SUB(sc, 0);
        SUB(sc, 1);
        // stage next super-chunk LAST: consumer loads are older in the vmcnt
        // FIFO, so their counted waits never drain this HBM stage (R10 lesson)
        if (sc < 7) STAGE(cur ^ 1, sc + 1);
        DRAIN_BARRIER();
    }
#undef SUB
#undef KSTEP
#undef STAGE

    // write partial numerator / denominator
    #pragma unroll
    for (int reg = 0; reg < 4; ++reg) {
        int row = jg * 4 + reg;
        float* prow = part + (((size_t)jh * NB + b) * NN + i0 + row) * NHF + h * NP;
        #pragma unroll
        for (int o = 0; o < 4; ++o)
            prow[o * 16 + r] = acc[o][reg];
        if (r == 0)
            dpart[(((size_t)jh * NB + b) * NH + h) * NN + i0 + row] = acc4[reg];
    }
}

// ---------------------------------------------------------------------------
// Kernel C: combine halves: out = ELU((n0+n1)/(d0+d1) + bias).
// Grid: B*N*NHF/4/256 = 4096 blocks x 256 thr, float4 per thread.
// ---------------------------------------------------------------------------
__global__ __launch_bounds__(256) void gat_reduce(
    const float* __restrict__ part,    // [2,B,N,NHF]
    const float* __restrict__ dpart,   // [2,B,H,N]
    const float* __restrict__ biases,  // [H,FP]
    float* __restrict__ out)           // [B,N,NHF]
{
    int gid = blockIdx.x * 256 + threadIdx.x;
    int row = gid >> 6;                // [0, B*N)
    int q   = gid & 63;                // float4 index within 256 feats
    int b = row >> 11, n = row & (NN - 1);
    int h = q >> 4;

    const f32x4* p4 = (const f32x4*)part;
    f32x4 n0 = p4[(size_t)row * 64 + q];
    f32x4 n1 = p4[(size_t)NB * NN * 64 + (size_t)row * 64 + q];
    size_t didx = ((size_t)b * NH + h) * NN + n;
    float d = dpart[didx] + dpart[(size_t)NB * NH * NN + didx];
    float rcp = 1.0f / d;
    f32x4 bias4 = ((const f32x4*)biases)[q];
    f32x4 y;
    #pragma unroll
    for (int e = 0; e < 4; ++e) {
        float v = fmaf(n0[e] + n1[e], rcp, bias4[e]);
        y[e] = (v > 0.f) ? v : (__expf(v) - 1.0f);   // ELU
    }
    ((f32x4*)out)[(size_t)row * 64 + q] = y;
}

// ---------------------------------------------------------------------------
// Fallback single-pass kernel (R10, proven 86us): used when d_ws too small.
// ---------------------------------------------------------------------------
__global__ __launch_bounds__(256)
__attribute__((amdgpu_waves_per_eu(4, 4)))
void gat_attn(
    const float* __restrict__ adj, const short* __restrict__ featsT,
    const float* __restrict__ s_out, const float* __restrict__ s_in,
    const float* __restrict__ biases, float* __restrict__ out)
{
    __shared__ __align__(16) float adj_lds[2][4096];

    int blk = ((blockIdx.x & 7) << 7) + (blockIdx.x >> 3);
    int b  = blk >> 7;
    int it = blk & 127;
    int i0 = it * 16;
    int tid = threadIdx.x;
    int h = tid >> 6;
    int lane = tid & 63;
    int r  = lane & 15;
    int jg = lane >> 4;

    const char* asrc[4];
    #pragma unroll
    for (int k = 0; k < 4; ++k) {
        int row = h * 4 + k;
        asrc[k] = (const char*)(adj + ((size_t)b * NN + i0 + row) * NN)
                  + ((lane ^ (row & 7)) << 4);
    }

#define STAGE(BUF, SC) do {                                                   \
        _Pragma("unroll")                                                     \
        for (int k = 0; k < 4; ++k)                                           \
            async16(asrc[k] + (size_t)(SC) * 1024,                            \
                    &adj_lds[BUF][(h * 4 + k) << 8]);                         \
    } while (0)

    STAGE(0, 0);

    float so = s_out[((size_t)b * NH + h) * NN + i0 + r];
    const float* sirow = s_in + ((size_t)b * NH + h) * NN + jg * 8;
    const short* vwave = featsT + (size_t)(b * NH + h) * NP * NN + jg * 512 + r * 8;
    int rsw = r & 7;
    int f0 = ((jg * 2)     ^ rsw) << 2;
    int f1 = ((jg * 2 + 1) ^ rsw) << 2;
    int rbase = r << 8;

    float bias_v[4];
    #pragma unroll
    for (int o = 0; o < 4; ++o) bias_v[o] = biases[h * NP + o * 16 + r];

    bf16x8 ones;
    #pragma unroll
    for (int e = 0; e < 8; ++e) ones[e] = (short)0x3F80;

    DRAIN_BARRIER();

    f32x4 acc[4] = {};
    f32x4 acc4 = {};

#define KSTEP(S, KS, Q0, Q1, V0, V1, V2, V3) do {                             \
        const float* ap = ab + rbase + (((S) * 16 + (KS) * 8) << 2);          \
        f32x4 a0 = *(const f32x4*)(ap + f0);                                  \
        f32x4 a1 = *(const f32x4*)(ap + f1);                                  \
        bf16x8 af;                                                            \
        _Pragma("unroll")                                                     \
        for (int e = 0; e < 8; ++e) {                                         \
            float av = (e < 4) ? a0[e] : a1[e - 4];                           \
            float sv = (e < 4) ? Q0[e] : Q1[e - 4];                           \
            float t = so + sv;                                                \
            float lr = fmaxf(t, 0.2f * t);                                    \
            float arg = fmaf(av, LOG2E, lr);                                  \
            float pe_ = exp2_fast(arg);                                       \
            float p = (av != 0.f) ? pe_ : 0.f;                                \
            __hip_bfloat16 hbv = __float2bfloat16(p);                         \
            af[e] = (short)__builtin_bit_cast(unsigned short, hbv);           \
        }                                                                     \
        acc[0] = __builtin_amdgcn_mfma_f32_16x16x32_bf16(af, V0, acc[0], 0, 0, 0); \
        acc[1] = __builtin_amdgcn_mfma_f32_16x16x32_bf16(af, V1, acc[1], 0, 0, 0); \
        acc[2] = __builtin_amdgcn_mfma_f32_16x16x32_bf16(af, V2, acc[2], 0, 0, 0); \
        acc[3] = __builtin_amdgcn_mfma_f32_16x16x32_bf16(af, V3, acc[3], 0, 0, 0); \
        acc4   = __builtin_amdgcn_mfma_f32_16x16x32_bf16(af, ones, acc4, 0, 0, 0); \
    } while (0)

#define SUB(SC, S) do {                                                       \
        const short* vp = vwave + (size_t)(((SC) * 32 + (S) * 8) << 9);       \
        bf16x8 v00 = *(const bf16x8*)(vp);                                    \
        bf16x8 v01 = *(const bf16x8*)(vp + 128);                              \
        bf16x8 v02 = *(const bf16x8*)(vp + 256);                              \
        bf16x8 v03 = *(const bf16x8*)(vp + 384);                              \
        bf16x8 v10 = *(const bf16x8*)(vp + 2048);                             \
        bf16x8 v11 = *(const bf16x8*)(vp + 2048 + 128);                       \
        bf16x8 v12 = *(const bf16x8*)(vp + 2048 + 256);                       \
        bf16x8 v13 = *(const bf16x8*)(vp + 2048 + 384);                       \
        const float* sip = sirow + (SC) * 256 + (S) * 64;                     \
        f32x4 q00 = *(const f32x4*)(sip);                                     \
        f32x4 q01 = *(const f32x4*)(sip + 4);                                 \
        f32x4 q10 = *(const f32x4*)(sip + 32);                                \
        f32x4 q11 = *(const f32x4*)(sip + 36);                                \
        KSTEP(S, 0, q00, q01, v00, v01, v02, v03);                            \
        KSTEP(S, 1, q10, q11, v10, v11, v12, v13);                            \
    } while (0)

    for (int sc = 0; sc < 8; ++sc) {
        int cur = sc & 1;
        const float* ab = &adj_lds[cur][0];
        SUB(sc, 0);
        SUB(sc, 1);
        SUB(sc, 2);
        SUB(sc, 3);
        if (sc < 7) STAGE(cur ^ 1, sc + 1);
        DRAIN_BARRIER();
    }
#undef SUB
#undef KSTEP
#undef STAGE

    #pragma unroll
    for (int reg = 0; reg < 4; ++reg) {
        int row = jg * 4 + reg;
        float rcp = 1.0f / acc4[reg];
        float* orow = out + ((size_t)b * NN + i0 + row) * NHF + h * NP;
        #pragma unroll
        for (int o = 0; o < 4; ++o) {
            float y = acc[o][reg] * rcp + bias_v[o];
            y = (y > 0.f) ? y : (__expf(y) - 1.0f);
            orow[o * 16 + r] = y;
        }
    }
}

extern "C" void kernel_launch(void* const* d_in, const int* in_sizes, int n_in,
                              void* d_out, int out_size, void* d_ws, size_t ws_size,
                              hipStream_t stream) {
    const float* x      = (const float*)d_in[0];  // node_feats [B,N,F]
    const float* adj    = (const float*)d_in[1];  // adjacency  [B,N,N]
    // d_in[2] = attn_mask -- NOT read; derived from adj (edge <=> adj != 0)
    const float* W      = (const float*)d_in[3];  // kernels    [H,F,FP]
    const float* biases = (const float*)d_in[4];  // [H,FP]
    const float* a_out  = (const float*)d_in[5];  // [H,FP]
    const float* a_in   = (const float*)d_in[6];  // [H,FP]
    float* out = (float*)d_out;

    char* ws = (char*)d_ws;
    short* featsT = (short*)ws;                                // 8 MB bf16, interleaved
    float* s_out  = (float*)(ws + 8388608);                    // 256 KB
    float* s_in   = (float*)(ws + 8388608 + 262144);           // 256 KB
    float* part   = (float*)(ws + 8912896);                    // 33.5 MB
    float* dpart  = (float*)(ws + 8912896 + 33554432);         // 512 KB
    const size_t need_split = 8912896ull + 33554432ull + 524288ull;

    gat_scores<<<256, 256, 0, stream>>>(x, W, a_out, a_in, s_out, s_in);
    gat_feats<<<NB * NH * (NN / 64), 256, 0, stream>>>(x, W, featsT);
    if (ws_size >= need_split) {
        gat_attn_part<<<NB * (NN / 16) * 2, 256, 0, stream>>>(adj, featsT, s_out, s_in, part, dpart);
        gat_reduce<<<NB * NN * NHF / 4 / 256, 256, 0, stream>>>(part, dpart, biases, out);
    } else {
        gat_attn<<<NB * (NN / 16), 256, 0, stream>>>(adj, featsT, s_out, s_in, biases, out);
    }
}

// Round 13
// 99.236 us; speedup vs baseline: 1.4028x; 1.0885x over previous
//
#include <hip/hip_runtime.h>
#include <hip/hip_bf16.h>

#define NB 8
#define NN 2048
#define NF 64      // in features
#define NP 64      // out features per head
#define NH 4
#define NHF 256    // NH*NP
#define LOG2E 1.4426950408889634f

typedef float f32x4 __attribute__((ext_vector_type(4)));
typedef short bf16x8 __attribute__((ext_vector_type(8)));
typedef short s16x4 __attribute__((ext_vector_type(4)));

// f32 -> bf16 bits, round-nearest-even
__device__ __forceinline__ short f2bf(float f) {
    unsigned u = __builtin_bit_cast(unsigned, f);
    unsigned r = (u + 0x7fffu + ((u >> 16) & 1u)) >> 16;
    return (short)r;
}

__device__ __forceinline__ float exp2_fast(float x) {
#if __has_builtin(__builtin_amdgcn_exp2f)
    return __builtin_amdgcn_exp2f(x);
#else
    float r;
    asm volatile("v_exp_f32 %0, %1\n\ts_nop 1" : "=v"(r) : "v"(x));
    return r;
#endif
}

__device__ __forceinline__ void async16(const void* g, void* l) {
    __builtin_amdgcn_global_load_lds(
        (const __attribute__((address_space(1))) void*)g,
        (__attribute__((address_space(3))) void*)l, 16, 0, 0);
}

// ---------------------------------------------------------------------------
// Kernel A1: s_out[b,h,n] = (x[b,n,:] . (W[h] @ a_out[h])) * LOG2E, same s_in.
// ---------------------------------------------------------------------------
__global__ __launch_bounds__(256) void gat_scores(
    const float* __restrict__ x, const float* __restrict__ W,
    const float* __restrict__ a_out, const float* __restrict__ a_in,
    float* __restrict__ s_out, float* __restrict__ s_in)
{
    __shared__ float co_lds[NH][NF];
    __shared__ float ci_lds[NH][NF];
    int tid = threadIdx.x;
    int h = tid >> 6, f = tid & 63;
    {
        float co = 0.f, ci = 0.f;
        const float* wrow = W + (h * NF + f) * NP;
        #pragma unroll 8
        for (int o = 0; o < NP; ++o) {
            float w = wrow[o];
            co = fmaf(w, a_out[h * NP + o], co);
            ci = fmaf(w, a_in[h * NP + o], ci);
        }
        co_lds[h][f] = co;
        ci_lds[h][f] = ci;
    }
    __syncthreads();
    int wid = tid >> 6, lane = tid & 63;
    float cov[NH], civ[NH];
    #pragma unroll
    for (int hh = 0; hh < NH; ++hh) { cov[hh] = co_lds[hh][lane]; civ[hh] = ci_lds[hh][lane]; }
    int base = blockIdx.x * 64 + wid * 16;     // global row in [0, B*N)
    for (int r = 0; r < 16; ++r) {
        int gn = base + r;
        float xv = x[(size_t)gn * NF + lane];
        #pragma unroll
        for (int hh = 0; hh < NH; ++hh) {
            float vo = xv * cov[hh];
            float vi = xv * civ[hh];
            #pragma unroll
            for (int s2 = 1; s2 < 64; s2 <<= 1) {
                vo += __shfl_xor(vo, s2, 64);
                vi += __shfl_xor(vi, s2, 64);
            }
            if (lane == 0) {
                int b = gn >> 11, n = gn & (NN - 1);
                s_out[((size_t)b * NH + hh) * NN + n] = vo * LOG2E;
                s_in [((size_t)b * NH + hh) * NN + n] = vi * LOG2E;
            }
        }
    }
}

// ---------------------------------------------------------------------------
// Kernel A2: featsT interleaved: element (feature o, node j) of head (b,h) at
// base(b,h) + (j>>3)*512 + o*8 + (j&7)  => V-frag loads are 256B-contiguous.
// ---------------------------------------------------------------------------
__global__ __launch_bounds__(256) void gat_feats(
    const float* __restrict__ x, const float* __restrict__ W,
    short* __restrict__ featsT)
{
    int blk = blockIdx.x;
    int nb = blk & 31;           // N/64 = 32
    int h  = (blk >> 5) & 3;
    int b  = blk >> 7;
    int tid = threadIdx.x, wid = tid >> 6, lane = tid & 63;
    int n0 = nb * 64 + wid * 16;
    int rA = lane & 15, g = lane >> 4;

    bf16x8 af[2];
    #pragma unroll
    for (int kk = 0; kk < 2; ++kk) {
        const float* xp = x + ((size_t)(b * NN) + n0 + rA) * NF + kk * 32 + g * 8;
        f32x4 x0 = *(const f32x4*)xp;
        f32x4 x1 = *(const f32x4*)(xp + 4);
        #pragma unroll
        for (int e = 0; e < 4; ++e) {
            af[kk][e]     = f2bf(x0[e]);
            af[kk][e + 4] = f2bf(x1[e]);
        }
    }
    f32x4 acc[4] = {};
    #pragma unroll
    for (int o = 0; o < 4; ++o) {
        #pragma unroll
        for (int kk = 0; kk < 2; ++kk) {
            bf16x8 bfv;
            #pragma unroll
            for (int e = 0; e < 8; ++e) {
                float wv = W[((size_t)h * NF + kk * 32 + g * 8 + e) * NP + o * 16 + rA];
                bfv[e] = f2bf(wv);
            }
            acc[o] = __builtin_amdgcn_mfma_f32_16x16x32_bf16(af[kk], bfv, acc[o], 0, 0, 0);
        }
    }
    size_t hb = (size_t)(b * NH + h) * NP * NN;
    int jq = n0 / 8 + (g >> 1);     // j>>3 for j = n0 + g*4
    int jr = (g & 1) * 4;           // j&7
    #pragma unroll
    for (int o = 0; o < 4; ++o) {
        s16x4 pk;
        pk[0] = f2bf(acc[o][0]);
        pk[1] = f2bf(acc[o][1]);
        pk[2] = f2bf(acc[o][2]);
        pk[3] = f2bf(acc[o][3]);
        *(s16x4*)(featsT + hb + (size_t)jq * 512 + (o * 16 + rA) * 8 + jr) = pk;
    }
}

// ---------------------------------------------------------------------------
// Kernel B: fused masked-softmax attention + PV (T3/T4 counted-vmcnt schedule).
// Grid: B*(N/16) = 1024 blocks x 256 thr (4 waves = 4 heads, 16 i-rows).
// 16 phases x 128 j; adj in a 3-buffer rotating LDS pipeline (3 x 8 KB),
// staged 2 phases ahead via global_load_lds. Per phase each wave:
//   compute(sc) ; STAGE(sc+2) ; s_waitcnt vmcnt(2) ; raw s_barrier
// vmcnt(2) retires the wave's OWN stage(sc+1) (every wave does this, so after
// the barrier the whole (sc+1) tile is landed) while stage(sc+2) stays in
// flight ACROSS the barrier -- no vmcnt(0) drain anywhere in the loop.
// Raw __builtin_amdgcn_s_barrier() (NOT __syncthreads) avoids the compiler's
// implicit full drain. sched_barrier(0) pins the [SUB|STAGE|wait|barrier]
// group order; any residual compiler reordering only strengthens the waits.
// XCD swizzle (R10): batch per XCD -> featsT slice L2-resident.
// ---------------------------------------------------------------------------
__global__ __launch_bounds__(256)
__attribute__((amdgpu_waves_per_eu(4, 4)))
void gat_attn(
    const float* __restrict__ adj,     // [B,N,N]
    const short* __restrict__ featsT,  // interleaved, see gat_feats
    const float* __restrict__ s_out,   // [B,H,N]  (prescaled by log2e)
    const float* __restrict__ s_in,    // [B,H,N]  (prescaled by log2e)
    const float* __restrict__ biases,  // [H,FP]
    float* __restrict__ out)           // [B,N,H*FP]
{
    __shared__ __align__(16) float adj_lds[3][2048];  // 3 x 8 KB: [16 rows][128 j]

    int blk = ((blockIdx.x & 7) << 7) + (blockIdx.x >> 3);  // XCD swizzle
    int b  = blk >> 7;
    int it = blk & 127;
    int i0 = it * 16;
    int tid = threadIdx.x;
    int h = tid >> 6;             // wave = head (wave-uniform)
    int lane = tid & 63;
    int r  = lane & 15;
    int jg = lane >> 4;

    // staging: per wave 2 calls/phase; call k covers rows h*4+2k (lanes 0-31)
    // and h*4+2k+1 (lanes 32-63), 512B each. Swizzle on the global source:
    // 16B-block b=lane&31 -> (b&24) | ((b&7) ^ (row&7)).
    const char* asrc[2];
    #pragma unroll
    for (int k = 0; k < 2; ++k) {
        int row = h * 4 + 2 * k + (lane >> 5);
        int bs = lane & 31;
        int swz = (bs & 24) | ((bs & 7) ^ (row & 7));
        asrc[k] = (const char*)(adj + ((size_t)b * NN + i0 + row) * NN) + (swz << 4);
    }

#define STAGE(BUF, SC) do {                                                   \
        _Pragma("unroll")                                                     \
        for (int k = 0; k < 2; ++k)                                           \
            async16(asrc[k] + (SC) * 512,                                     \
                    &adj_lds[BUF][(h * 4 + 2 * k) << 7]);                     \
    } while (0)

    // prologue: stage phases 0,1 into bufs 0,1
    STAGE(0, 0);
    STAGE(1, 1);

    float so = s_out[((size_t)b * NH + h) * NN + i0 + r];
    const float* sirow = s_in + ((size_t)b * NH + h) * NN + jg * 8;
    const short* vwave = featsT + (size_t)(b * NH + h) * NP * NN + jg * 512 + r * 8;
    int rsw = r & 7;
    int f0 = ((jg * 2)     ^ rsw) << 2;   // float offset in each 32-float group
    int f1 = ((jg * 2 + 1) ^ rsw) << 2;
    int rbase = r << 7;                   // row stride = 128 floats (512B)

    float bias_v[4];
    #pragma unroll
    for (int o = 0; o < 4; ++o) bias_v[o] = biases[h * NP + o * 16 + r];

    bf16x8 ones;
    #pragma unroll
    for (int e = 0; e < 8; ++e) ones[e] = (short)0x3F80;   // bf16 1.0

    __builtin_amdgcn_sched_barrier(0);
    asm volatile("s_waitcnt vmcnt(2)" ::: "memory");   // own stage(0) landed
    __builtin_amdgcn_sched_barrier(0);
    __builtin_amdgcn_s_barrier();                      // all waves' stage(0) landed
    __builtin_amdgcn_sched_barrier(0);

    f32x4 acc[4] = {};
    f32x4 acc4 = {};   // row-sum accumulator (denominator)

// one 16x32 P-subtile: 2 LDS adj reads + P-compute + 5 MFMA
#define KSTEP(S, KS, Q0, Q1, V0, V1, V2, V3) do {                             \
        const float* ap = ab + rbase + (S) * 64 + (KS) * 32;                  \
        f32x4 a0 = *(const f32x4*)(ap + f0);                                  \
        f32x4 a1 = *(const f32x4*)(ap + f1);                                  \
        bf16x8 af;                                                            \
        _Pragma("unroll")                                                     \
        for (int e = 0; e < 8; ++e) {                                         \
            float av = (e < 4) ? a0[e] : a1[e - 4];                           \
            float sv = (e < 4) ? Q0[e] : Q1[e - 4];                           \
            float t = so + sv;                                                \
            float lr = fmaxf(t, 0.2f * t);                                    \
            float arg = fmaf(av, LOG2E, lr);                                  \
            float pe_ = exp2_fast(arg);                                       \
            float p = (av != 0.f) ? pe_ : 0.f;                                \
            __hip_bfloat16 hbv = __float2bfloat16(p);                         \
            af[e] = (short)__builtin_bit_cast(unsigned short, hbv);           \
        }                                                                     \
        acc[0] = __builtin_amdgcn_mfma_f32_16x16x32_bf16(af, V0, acc[0], 0, 0, 0); \
        acc[1] = __builtin_amdgcn_mfma_f32_16x16x32_bf16(af, V1, acc[1], 0, 0, 0); \
        acc[2] = __builtin_amdgcn_mfma_f32_16x16x32_bf16(af, V2, acc[2], 0, 0, 0); \
        acc[3] = __builtin_amdgcn_mfma_f32_16x16x32_bf16(af, V3, acc[3], 0, 0, 0); \
        acc4   = __builtin_amdgcn_mfma_f32_16x16x32_bf16(af, ones, acc4, 0, 0, 0); \
    } while (0)

// one 64-j sub-chunk U (global index): V (8x16B) + si (4x16B), 2 KSTEPs
#define SUB(S, U) do {                                                        \
        const short* vp = vwave + (size_t)(U) * 4096;                         \
        bf16x8 v00 = *(const bf16x8*)(vp);                                    \
        bf16x8 v01 = *(const bf16x8*)(vp + 128);                              \
        bf16x8 v02 = *(const bf16x8*)(vp + 256);                              \
        bf16x8 v03 = *(const bf16x8*)(vp + 384);                              \
        bf16x8 v10 = *(const bf16x8*)(vp + 2048);                             \
        bf16x8 v11 = *(const bf16x8*)(vp + 2048 + 128);                       \
        bf16x8 v12 = *(const bf16x8*)(vp + 2048 + 256);                       \
        bf16x8 v13 = *(const bf16x8*)(vp + 2048 + 384);                       \
        const float* sip = sirow + (U) * 64;                                  \
        f32x4 q00 = *(const f32x4*)(sip);                                     \
        f32x4 q01 = *(const f32x4*)(sip + 4);                                 \
        f32x4 q10 = *(const f32x4*)(sip + 32);                                \
        f32x4 q11 = *(const f32x4*)(sip + 36);                                \
        KSTEP(S, 0, q00, q01, v00, v01, v02, v03);                            \
        KSTEP(S, 1, q10, q11, v10, v11, v12, v13);                            \
    } while (0)

    int cur = 0;
    for (int sc = 0; sc < 16; ++sc) {
        const float* ab = &adj_lds[cur][0];
        SUB(0, 2 * sc);
        SUB(1, 2 * sc + 1);
        __builtin_amdgcn_sched_barrier(0);
        if (sc < 14) {
            int stg = cur + 2; if (stg >= 3) stg -= 3;
            STAGE(stg, sc + 2);
            __builtin_amdgcn_sched_barrier(0);
            // retire own stage(sc+1); stage(sc+2) stays in flight across barrier
            asm volatile("s_waitcnt vmcnt(2)" ::: "memory");
        } else if (sc == 14) {
            // last stage (15) must land before phase 15
            asm volatile("s_waitcnt vmcnt(0)" ::: "memory");
        }
        __builtin_amdgcn_sched_barrier(0);
        if (sc < 15) __builtin_amdgcn_s_barrier();
        __builtin_amdgcn_sched_barrier(0);
        cur = (cur + 1 == 3) ? 0 : cur + 1;
    }
#undef SUB
#undef KSTEP
#undef STAGE

    // epilogue: denominator for row (jg*4+reg) is acc4[reg] in every lane of
    // the matching group (all-ones B => every column holds the row sum).
    #pragma unroll
    for (int reg = 0; reg < 4; ++reg) {
        int row = jg * 4 + reg;                  // D row = (lane>>4)*4 + reg
        float rcp = 1.0f / acc4[reg];
        float* orow = out + ((size_t)b * NN + i0 + row) * NHF + h * NP;
        #pragma unroll
        for (int o = 0; o < 4; ++o) {
            float y = acc[o][reg] * rcp + bias_v[o];
            y = (y > 0.f) ? y : (__expf(y) - 1.0f);   // ELU
            orow[o * 16 + r] = y;
        }
    }
}

extern "C" void kernel_launch(void* const* d_in, const int* in_sizes, int n_in,
                              void* d_out, int out_size, void* d_ws, size_t ws_size,
                              hipStream_t stream) {
    const float* x      = (const float*)d_in[0];  // node_feats [B,N,F]
    const float* adj    = (const float*)d_in[1];  // adjacency  [B,N,N]
    // d_in[2] = attn_mask -- NOT read; derived from adj (edge <=> adj != 0)
    const float* W      = (const float*)d_in[3];  // kernels    [H,F,FP]
    const float* biases = (const float*)d_in[4];  // [H,FP]
    const float* a_out  = (const float*)d_in[5];  // [H,FP]
    const float* a_in   = (const float*)d_in[6];  // [H,FP]
    float* out = (float*)d_out;

    char* ws = (char*)d_ws;
    short* featsT = (short*)ws;                                // 8 MB bf16, interleaved
    float* s_out  = (float*)(ws + 8388608);                    // 256 KB
    float* s_in   = (float*)(ws + 8388608 + 262144);           // 256 KB

    gat_scores<<<256, 256, 0, stream>>>(x, W, a_out, a_in, s_out, s_in);
    gat_feats<<<NB * NH * (NN / 64), 256, 0, stream>>>(x, W, featsT);
    gat_attn<<<NB * (NN / 16), 256, 0, stream>>>(adj, featsT, s_out, s_in, biases, out);
}

// Round 14
// 91.496 us; speedup vs baseline: 1.5215x; 1.0846x over previous
//
#include <hip/hip_runtime.h>
#include <hip/hip_bf16.h>

#define NB 8
#define NN 2048
#define NF 64      // in features
#define NP 64      // out features per head
#define NH 4
#define NHF 256    // NH*NP
#define LOG2E 1.4426950408889634f

typedef float f32x4 __attribute__((ext_vector_type(4)));
typedef short bf16x8 __attribute__((ext_vector_type(8)));
typedef short s16x4 __attribute__((ext_vector_type(4)));

// f32 -> bf16 bits, round-nearest-even
__device__ __forceinline__ short f2bf(float f) {
    unsigned u = __builtin_bit_cast(unsigned, f);
    unsigned r = (u + 0x7fffu + ((u >> 16) & 1u)) >> 16;
    return (short)r;
}

__device__ __forceinline__ float exp2_fast(float x) {
#if __has_builtin(__builtin_amdgcn_exp2f)
    return __builtin_amdgcn_exp2f(x);
#else
    float r;
    asm volatile("v_exp_f32 %0, %1\n\ts_nop 1" : "=v"(r) : "v"(x));
    return r;
#endif
}

__device__ __forceinline__ void async16(const void* g, void* l) {
    __builtin_amdgcn_global_load_lds(
        (const __attribute__((address_space(1))) void*)g,
        (__attribute__((address_space(3))) void*)l, 16, 0, 0);
}

// ---------------------------------------------------------------------------
// Kernel A1: s_out[b,h,n] = (x[b,n,:] . (W[h] @ a_out[h])) * LOG2E, same s_in.
// ---------------------------------------------------------------------------
__global__ __launch_bounds__(256) void gat_scores(
    const float* __restrict__ x, const float* __restrict__ W,
    const float* __restrict__ a_out, const float* __restrict__ a_in,
    float* __restrict__ s_out, float* __restrict__ s_in)
{
    __shared__ float co_lds[NH][NF];
    __shared__ float ci_lds[NH][NF];
    int tid = threadIdx.x;
    int h = tid >> 6, f = tid & 63;
    {
        float co = 0.f, ci = 0.f;
        const float* wrow = W + (h * NF + f) * NP;
        #pragma unroll 8
        for (int o = 0; o < NP; ++o) {
            float w = wrow[o];
            co = fmaf(w, a_out[h * NP + o], co);
            ci = fmaf(w, a_in[h * NP + o], ci);
        }
        co_lds[h][f] = co;
        ci_lds[h][f] = ci;
    }
    __syncthreads();
    int wid = tid >> 6, lane = tid & 63;
    float cov[NH], civ[NH];
    #pragma unroll
    for (int hh = 0; hh < NH; ++hh) { cov[hh] = co_lds[hh][lane]; civ[hh] = ci_lds[hh][lane]; }
    int base = blockIdx.x * 64 + wid * 16;     // global row in [0, B*N)
    for (int r = 0; r < 16; ++r) {
        int gn = base + r;
        float xv = x[(size_t)gn * NF + lane];
        #pragma unroll
        for (int hh = 0; hh < NH; ++hh) {
            float vo = xv * cov[hh];
            float vi = xv * civ[hh];
            #pragma unroll
            for (int s2 = 1; s2 < 64; s2 <<= 1) {
                vo += __shfl_xor(vo, s2, 64);
                vi += __shfl_xor(vi, s2, 64);
            }
            if (lane == 0) {
                int b = gn >> 11, n = gn & (NN - 1);
                s_out[((size_t)b * NH + hh) * NN + n] = vo * LOG2E;
                s_in [((size_t)b * NH + hh) * NN + n] = vi * LOG2E;
            }
        }
    }
}

// ---------------------------------------------------------------------------
// Kernel A2: featsT interleaved: element (feature o, node j) of head (b,h) at
// base(b,h) + (j>>3)*512 + o*8 + (j&7). XCD swizzle: batch b written by XCD b
// so gat_attn's reads (same mapping) hit that XCD's L2.
// ---------------------------------------------------------------------------
__global__ __launch_bounds__(256) void gat_feats(
    const float* __restrict__ x, const float* __restrict__ W,
    short* __restrict__ featsT)
{
    int blk = ((blockIdx.x & 7) << 7) | (blockIdx.x >> 3);  // batch = bid&7 = XCD
    int nb = blk & 31;           // N/64 = 32
    int h  = (blk >> 5) & 3;
    int b  = blk >> 7;
    int tid = threadIdx.x, wid = tid >> 6, lane = tid & 63;
    int n0 = nb * 64 + wid * 16;
    int rA = lane & 15, g = lane >> 4;

    bf16x8 af[2];
    #pragma unroll
    for (int kk = 0; kk < 2; ++kk) {
        const float* xp = x + ((size_t)(b * NN) + n0 + rA) * NF + kk * 32 + g * 8;
        f32x4 x0 = *(const f32x4*)xp;
        f32x4 x1 = *(const f32x4*)(xp + 4);
        #pragma unroll
        for (int e = 0; e < 4; ++e) {
            af[kk][e]     = f2bf(x0[e]);
            af[kk][e + 4] = f2bf(x1[e]);
        }
    }
    f32x4 acc[4] = {};
    #pragma unroll
    for (int o = 0; o < 4; ++o) {
        #pragma unroll
        for (int kk = 0; kk < 2; ++kk) {
            bf16x8 bfv;
            #pragma unroll
            for (int e = 0; e < 8; ++e) {
                float wv = W[((size_t)h * NF + kk * 32 + g * 8 + e) * NP + o * 16 + rA];
                bfv[e] = f2bf(wv);
            }
            acc[o] = __builtin_amdgcn_mfma_f32_16x16x32_bf16(af[kk], bfv, acc[o], 0, 0, 0);
        }
    }
    size_t hb = (size_t)(b * NH + h) * NP * NN;
    int jq = n0 / 8 + (g >> 1);     // j>>3 for j = n0 + g*4
    int jr = (g & 1) * 4;           // j&7
    #pragma unroll
    for (int o = 0; o < 4; ++o) {
        s16x4 pk;
        pk[0] = f2bf(acc[o][0]);
        pk[1] = f2bf(acc[o][1]);
        pk[2] = f2bf(acc[o][2]);
        pk[3] = f2bf(acc[o][3]);
        *(s16x4*)(featsT + hb + (size_t)jq * 512 + (o * 16 + rA) * 8 + jr) = pk;
    }
}

// ---------------------------------------------------------------------------
// Kernel B: fused masked-softmax attention + PV. ALL operands via LDS.
// Grid: B*(N/64) = 256 blocks x 1024 thr (16 waves = 4 heads x 4 i-strips).
// Per 64-j phase, stage via global_load_lds: adj 16KB (3-buf, 2-ahead, shared
// by 16 waves), V 8KB/head (2-buf, 1-ahead, shared by 4 i-waves -> 4x less
// featsT L2 traffic), si 1KB (2-buf). Consumer reads are ds_read (lgkmcnt,
// decoupled from the vmcnt staging FIFO). Uniform counted vmcnt(1) + raw
// s_barrier per phase (R13 discipline) -- no vmcnt(0) drain in the loop.
// adj source-swizzled (slot ^ row&7) -> conflict-free ds_read_b128.
// ---------------------------------------------------------------------------
__global__ __launch_bounds__(1024, 4) void gat_attn(
    const float* __restrict__ adj,     // [B,N,N]
    const short* __restrict__ featsT,  // interleaved, see gat_feats
    const float* __restrict__ s_out,   // [B,H,N]  (prescaled by log2e)
    const float* __restrict__ s_in,    // [B,H,N]  (prescaled by log2e)
    const float* __restrict__ biases,  // [H,FP]
    float* __restrict__ out)           // [B,N,H*FP]
{
    __shared__ __align__(16) float adj_lds[3][64][64];  // 48KB
    __shared__ __align__(16) short v_lds[2][4][4096];   // 64KB
    __shared__ __align__(16) float si_lds[2][256];      // 2KB

    int blk = ((blockIdx.x & 7) << 5) | (blockIdx.x >> 3);  // batch = XCD
    int b  = blk >> 5;
    int it = blk & 31;
    int i0 = it * 64;
    int tid = threadIdx.x;
    int wid = tid >> 6;
    int h  = wid & 3;             // head
    int is = wid >> 2;            // i-strip (16 rows each)
    int lane = tid & 63;
    int r  = lane & 15;
    int jg = lane >> 4;

    // ---- early scalar-path loads (before any staging: stay oldest in FIFO)
    float so = s_out[((size_t)b * NH + h) * NN + i0 + is * 16 + r];
    float bias_v[4];
    #pragma unroll
    for (int o = 0; o < 4; ++o) bias_v[o] = biases[h * NP + o * 16 + r];
    bf16x8 ones;
    #pragma unroll
    for (int e = 0; e < 8; ++e) ones[e] = (short)0x3F80;   // bf16 1.0

    // ---- per-lane staging sources
    int arow  = wid * 4 + (lane >> 4);                 // local adj row this lane serves
    int aslot = (lane & 15) ^ (arow & 7);              // source-swizzled 16B slot
    const char* adj_src = (const char*)(adj + ((size_t)b * NN + i0 + arow) * NN)
                          + (aslot << 4);
    const short* v_src = featsT + (size_t)(b * NH + h) * NP * NN
                         + (is * 2) * 512 + lane * 8;  // groups is*2, is*2+1
    const float* si_src = s_in + ((size_t)b * NH + (lane >> 4)) * NN + (lane & 15) * 4;

#define STAGE_VSI(PH) do {                                                    \
        int vb_ = (PH) & 1;                                                   \
        const short* vs_ = v_src + (size_t)(PH) * 4096;                       \
        async16(vs_,       &v_lds[vb_][h][(is * 2) * 512]);                   \
        async16(vs_ + 512, &v_lds[vb_][h][(is * 2 + 1) * 512]);               \
        if (wid == 0) async16(si_src + (PH) * 64, &si_lds[vb_][0]);           \
    } while (0)
#define STAGE_ADJ(BUF, PH)                                                    \
        async16(adj_src + (size_t)(PH) * 256, &adj_lds[BUF][wid * 4][0])

    // prologue: phase 0 (V,si,adj) + adj 1 (2-ahead)
    STAGE_VSI(0);
    STAGE_ADJ(0, 0);
    STAGE_ADJ(1, 1);
    __builtin_amdgcn_sched_barrier(0);
    asm volatile("s_waitcnt vmcnt(1)" ::: "memory");   // phase-0 set landed
    __builtin_amdgcn_sched_barrier(0);
    __builtin_amdgcn_s_barrier();
    __builtin_amdgcn_sched_barrier(0);

    // ---- per-lane read offsets (within buffers)
    int aoff = (is * 16 + r) * 64;                // adj row float offset
    int sA = ((jg * 2)     ^ (r & 7)) * 4;        // swizzled slot float offsets
    int sB = ((jg * 2 + 1) ^ (r & 7)) * 4;
    int voff  = jg * 512 + r * 8;                 // short offset in head V buffer
    int sioff = h * 64 + jg * 8;                  // float offset in si buffer

    f32x4 acc[4] = {};
    f32x4 acc4 = {};

#define KSTEP(K) do {                                                         \
        const float* ar = ab + aoff + (K) * 32;                               \
        f32x4 a0 = *(const f32x4*)(ar + sA);                                  \
        f32x4 a1 = *(const f32x4*)(ar + sB);                                  \
        const float* sip = sb + sioff + (K) * 32;                             \
        f32x4 q0 = *(const f32x4*)(sip);                                      \
        f32x4 q1 = *(const f32x4*)(sip + 4);                                  \
        const short* vp = vb_p + (K) * 2048 + voff;                           \
        bf16x8 v0 = *(const bf16x8*)(vp);                                     \
        bf16x8 v1 = *(const bf16x8*)(vp + 128);                               \
        bf16x8 v2 = *(const bf16x8*)(vp + 256);                               \
        bf16x8 v3 = *(const bf16x8*)(vp + 384);                               \
        bf16x8 af;                                                            \
        _Pragma("unroll")                                                     \
        for (int e = 0; e < 8; ++e) {                                         \
            float av = (e < 4) ? a0[e] : a1[e - 4];                           \
            float sv = (e < 4) ? q0[e] : q1[e - 4];                           \
            float t = so + sv;                                                \
            float lr = fmaxf(t, 0.2f * t);                                    \
            float arg = fmaf(av, LOG2E, lr);                                  \
            float pe_ = exp2_fast(arg);                                       \
            float p = (av != 0.f) ? pe_ : 0.f;                                \
            __hip_bfloat16 hbv = __float2bfloat16(p);                         \
            af[e] = (short)__builtin_bit_cast(unsigned short, hbv);           \
        }                                                                     \
        acc[0] = __builtin_amdgcn_mfma_f32_16x16x32_bf16(af, v0, acc[0], 0, 0, 0); \
        acc[1] = __builtin_amdgcn_mfma_f32_16x16x32_bf16(af, v1, acc[1], 0, 0, 0); \
        acc[2] = __builtin_amdgcn_mfma_f32_16x16x32_bf16(af, v2, acc[2], 0, 0, 0); \
        acc[3] = __builtin_amdgcn_mfma_f32_16x16x32_bf16(af, v3, acc[3], 0, 0, 0); \
        acc4   = __builtin_amdgcn_mfma_f32_16x16x32_bf16(af, ones, acc4, 0, 0, 0); \
    } while (0)

    int cur = 0;   // adj buffer for current phase
    for (int sc = 0; sc < 32; ++sc) {
        const float* ab   = &adj_lds[cur][0][0];
        const short* vb_p = &v_lds[sc & 1][h][0];
        const float* sb   = &si_lds[sc & 1][0];
        KSTEP(0);
        KSTEP(1);
        __builtin_amdgcn_sched_barrier(0);
        if (sc < 31) STAGE_VSI(sc + 1);
        if (sc < 30) {
            int a2 = cur + 2; if (a2 >= 3) a2 -= 3;
            STAGE_ADJ(a2, sc + 2);
        }
        __builtin_amdgcn_sched_barrier(0);
        if (sc < 30) {
            // retire phase sc+1 set (adj[sc+1], V/si[sc+1]); adj[sc+2] stays in flight
            asm volatile("s_waitcnt vmcnt(1) lgkmcnt(0)" ::: "memory");
        } else if (sc == 30) {
            asm volatile("s_waitcnt vmcnt(0) lgkmcnt(0)" ::: "memory");
        }
        __builtin_amdgcn_sched_barrier(0);
        if (sc < 31) __builtin_amdgcn_s_barrier();
        __builtin_amdgcn_sched_barrier(0);
        cur = (cur + 1 == 3) ? 0 : cur + 1;
    }
#undef KSTEP
#undef STAGE_VSI
#undef STAGE_ADJ

    // epilogue: denominator for row (jg*4+reg) is acc4[reg] in every lane of
    // the matching group (all-ones B => every column holds the row sum).
    #pragma unroll
    for (int reg = 0; reg < 4; ++reg) {
        int row = i0 + is * 16 + jg * 4 + reg;       // D row = (lane>>4)*4 + reg
        float rcp = 1.0f / acc4[reg];
        float* orow = out + ((size_t)b * NN + row) * NHF + h * NP;
        #pragma unroll
        for (int o = 0; o < 4; ++o) {
            float y = acc[o][reg] * rcp + bias_v[o];
            y = (y > 0.f) ? y : (__expf(y) - 1.0f);   // ELU
            orow[o * 16 + r] = y;
        }
    }
}

extern "C" void kernel_launch(void* const* d_in, const int* in_sizes, int n_in,
                              void* d_out, int out_size, void* d_ws, size_t ws_size,
                              hipStream_t stream) {
    const float* x      = (const float*)d_in[0];  // node_feats [B,N,F]
    const float* adj    = (const float*)d_in[1];  // adjacency  [B,N,N]
    // d_in[2] = attn_mask -- NOT read; derived from adj (edge <=> adj != 0)
    const float* W      = (const float*)d_in[3];  // kernels    [H,F,FP]
    const float* biases = (const float*)d_in[4];  // [H,FP]
    const float* a_out  = (const float*)d_in[5];  // [H,FP]
    const float* a_in   = (const float*)d_in[6];  // [H,FP]
    float* out = (float*)d_out;

    char* ws = (char*)d_ws;
    short* featsT = (short*)ws;                                // 8 MB bf16, interleaved
    float* s_out  = (float*)(ws + 8388608);                    // 256 KB
    float* s_in   = (float*)(ws + 8388608 + 262144);           // 256 KB

    gat_scores<<<256, 256, 0, stream>>>(x, W, a_out, a_in, s_out, s_in);
    gat_feats<<<NB * NH * (NN / 64), 256, 0, stream>>>(x, W, featsT);
    gat_attn<<<NB * (NN / 64), 1024, 0, stream>>>(adj, featsT, s_out, s_in, biases, out);
}